// Round 1
// baseline (1201.690 us; speedup 1.0000x reference)
//
#include <hip/hip_runtime.h>
#include <cmath>

// Problem constants (match reference)
constexpr int Bn  = 512;
constexpr int Cn  = 256;
constexpr int Tn  = 256;
constexpr int Kn  = 5;
constexpr int Gn  = 8;
constexpr int CPG = Cn / Gn;   // 32 channels per group
constexpr int CI_TILE = 32;
constexpr float EPSf = 1e-5f;

// One workgroup per (b, g). 256 threads:
//   tl = tid & 127  -> owns t = 2*tl, 2*tl+1
//   ch = tid >> 7   -> owns channels [g*32 + ch*16, +16)
// acc[16][2] per thread; x staged in LDS per 32-ci tile; W via scalar loads.
__global__ __launch_bounds__(256)
void conv_gn_mish(const float* __restrict__ x,      // [B][C][T]
                  const int*   __restrict__ expert, // [B]
                  const float* __restrict__ W,      // [E][C][C][K]
                  const float* __restrict__ bias,   // [E][C]
                  const float* __restrict__ gamma,  // [E][C]
                  const float* __restrict__ beta,   // [E][C]
                  float*       __restrict__ out)    // [B][C][T]
{
    const int bg = blockIdx.x;
    const int b  = bg >> 3;     // / Gn
    const int g  = bg & 7;      // % Gn
    const int e  = __builtin_amdgcn_readfirstlane(expert[b]);

    const int tid = threadIdx.x;
    const int tl  = tid & 127;
    // wave-uniform co-half -> SGPR so W addressing scalarizes (s_load)
    const int ch  = __builtin_amdgcn_readfirstlane(tid >> 7);
    const int t0  = tl * 2;

    __shared__ float xs[CI_TILE][Tn + 8]; // cols: x[t] at [t+2]; [0,1],[258,259] = 0 halo

    float acc[16][2];
#pragma unroll
    for (int i = 0; i < 16; ++i) { acc[i][0] = 0.f; acc[i][1] = 0.f; }

    const int co_base = g * CPG + ch * 16;

    for (int ct = 0; ct < Cn / CI_TILE; ++ct) {
        __syncthreads();
        const float* xrow = x + ((size_t)b * Cn + ct * CI_TILE) * Tn;
#pragma unroll
        for (int i = 0; i < CI_TILE; ++i)
            xs[i][2 + tid] = xrow[(size_t)i * Tn + tid];
        if (tid < CI_TILE) {
            xs[tid][0] = 0.f;
            xs[tid][1] = 0.f;
            xs[tid][Tn + 2] = 0.f;
            xs[tid][Tn + 3] = 0.f;
        }
        __syncthreads();

        const float* wbase =
            W + (((size_t)e * Cn + co_base) * Cn + ct * CI_TILE) * Kn;

        for (int ci = 0; ci < CI_TILE; ++ci) {
            float xv[6];
#pragma unroll
            for (int j = 0; j < 6; ++j) xv[j] = xs[ci][t0 + j];

            const float* wp = wbase + ci * Kn;
#pragma unroll
            for (int co = 0; co < 16; ++co) {
                const float* wc = wp + co * (Cn * Kn);  // uniform -> s_load
                const float w0 = wc[0], w1 = wc[1], w2 = wc[2],
                            w3 = wc[3], w4 = wc[4];
                acc[co][0] = fmaf(w0, xv[0], acc[co][0]);
                acc[co][0] = fmaf(w1, xv[1], acc[co][0]);
                acc[co][0] = fmaf(w2, xv[2], acc[co][0]);
                acc[co][0] = fmaf(w3, xv[3], acc[co][0]);
                acc[co][0] = fmaf(w4, xv[4], acc[co][0]);
                acc[co][1] = fmaf(w0, xv[1], acc[co][1]);
                acc[co][1] = fmaf(w1, xv[2], acc[co][1]);
                acc[co][1] = fmaf(w2, xv[3], acc[co][1]);
                acc[co][1] = fmaf(w3, xv[4], acc[co][1]);
                acc[co][1] = fmaf(w4, xv[5], acc[co][1]);
            }
        }
    }

    // bias + GroupNorm partial stats
    float s1 = 0.f, s2 = 0.f;
#pragma unroll
    for (int co = 0; co < 16; ++co) {
        const float bv = bias[e * Cn + co_base + co];
        acc[co][0] += bv;
        acc[co][1] += bv;
        s1 += acc[co][0] + acc[co][1];
        s2 += acc[co][0] * acc[co][0] + acc[co][1] * acc[co][1];
    }

    // 64-lane wave reduce, then 4-wave LDS reduce
#pragma unroll
    for (int off = 32; off > 0; off >>= 1) {
        s1 += __shfl_xor(s1, off);
        s2 += __shfl_xor(s2, off);
    }
    __shared__ float r1[4], r2[4];
    const int wid  = tid >> 6;
    const int lane = tid & 63;
    if (lane == 0) { r1[wid] = s1; r2[wid] = s2; }
    __syncthreads();
    s1 = r1[0] + r1[1] + r1[2] + r1[3];
    s2 = r2[0] + r2[1] + r2[2] + r2[3];

    constexpr float inv_n = 1.0f / (CPG * Tn);
    const float mu   = s1 * inv_n;
    const float var  = fmaf(-mu, mu, s2 * inv_n);   // E[y^2] - mu^2 (biased, ddof=0)
    const float rstd = rsqrtf(var + EPSf);

    float* orow = out + ((size_t)b * Cn + co_base) * Tn + t0;
#pragma unroll
    for (int co = 0; co < 16; ++co) {
        const float gm = gamma[e * Cn + co_base + co];
        const float bt = beta[e * Cn + co_base + co];
        const float y0 = fmaf((acc[co][0] - mu) * rstd, gm, bt);
        const float y1 = fmaf((acc[co][1] - mu) * rstd, gm, bt);
        // Mish: y * tanh(softplus(y)); softplus(y) ~= y for y > 20 (err < 2e-9)
        const float sp0 = (y0 > 20.f) ? y0 : log1pf(expf(y0));
        const float sp1 = (y1 > 20.f) ? y1 : log1pf(expf(y1));
        float2 o;
        o.x = y0 * tanhf(sp0);
        o.y = y1 * tanhf(sp1);
        *reinterpret_cast<float2*>(orow + (size_t)co * Tn) = o;
    }
}

extern "C" void kernel_launch(void* const* d_in, const int* in_sizes, int n_in,
                              void* d_out, int out_size, void* d_ws, size_t ws_size,
                              hipStream_t stream) {
    const float* x      = (const float*)d_in[0];
    const int*   expert = (const int*)  d_in[1];
    const float* W      = (const float*)d_in[2];
    const float* bias   = (const float*)d_in[3];
    const float* gamma  = (const float*)d_in[4];
    const float* beta   = (const float*)d_in[5];
    float* out = (float*)d_out;

    dim3 grid(Bn * Gn);
    dim3 block(256);
    hipLaunchKernelGGL(conv_gn_mish, grid, block, 0, stream,
                       x, expert, W, bias, gamma, beta, out);
}

// Round 2
// 228.333 us; speedup vs baseline: 5.2629x; 5.2629x over previous
//
#include <hip/hip_runtime.h>
#include <cmath>

constexpr int Bn = 512, Cn = 256, Tn = 256, En = 8;
constexpr float EPSf = 1e-5f;

using bf16x8 = __attribute__((ext_vector_type(8))) short;
using f32x4  = __attribute__((ext_vector_type(4))) float;

__device__ __forceinline__ ushort f2bf(float f) {
    uint u = __builtin_bit_cast(uint, f);
    uint r = u + 0x7FFFu + ((u >> 16) & 1u);   // RNE
    return (ushort)(r >> 16);
}

// Pre-kernel: W fp32 [E][co][ci][K] -> Wws bf16 [E][k][co][ci]
__global__ __launch_bounds__(256)
void wconv_kernel(const float* __restrict__ Wf, ushort* __restrict__ Wws) {
    int idx = blockIdx.x * 256 + threadIdx.x;   // e*65536 + co*256 + ci
    int ci = idx & 255, co = (idx >> 8) & 255, e = idx >> 16;
    const float* src = Wf + (size_t)idx * 5;
#pragma unroll
    for (int k = 0; k < 5; ++k)
        Wws[(((size_t)(e * 5 + k) * 256 + co) << 8) + ci] = f2bf(src[k]);
}

// Main: block = (b, group-pair). M=64 co, N=256 t, K=256ci x 5k.
// Wave w owns t-slice [w*64, w*64+64): 4x4 tiles of 16x16, acc 64 VGPR.
// LDS: xT[t'][ci] bf16, t' = t+2 (halo rows 0,1,258,259 = zero), row = 40 bf16.
template<bool USE_WS>
__global__ __launch_bounds__(256)
void conv_mfma(const float* __restrict__ x, const int* __restrict__ expert,
               const float* __restrict__ Wf, const ushort* __restrict__ Wws,
               const float* __restrict__ bias, const float* __restrict__ gamma,
               const float* __restrict__ beta, float* __restrict__ out) {
    // XCD-chunked swizzle: 2048 blocks, 256 per XCD, same-b blocks contiguous
    int id = blockIdx.x;
    int wg = (id & 7) * 256 + (id >> 3);
    int b  = wg >> 2;
    int gp = wg & 3;
    int e  = __builtin_amdgcn_readfirstlane(expert[b]);
    const int cb = gp * 64;

    const int tid = threadIdx.x;
    const int w = tid >> 6, l = tid & 63, q = l >> 4, r = l & 15;

    __shared__ ushort xT[260 * 40];
    __shared__ float red[4][4];

    f32x4 acc[4][4];
#pragma unroll
    for (int m = 0; m < 4; ++m)
#pragma unroll
        for (int n = 0; n < 4; ++n) acc[m][n] = f32x4{0.f, 0.f, 0.f, 0.f};

    // zero halo rows once (never overwritten by staging)
    if (tid < 4) {
        int row = (tid < 2) ? tid : (256 + tid);   // 0,1,258,259
#pragma unroll
        for (int i = 0; i < 10; ++i)
            *reinterpret_cast<uint2*>(&xT[row * 40 + i * 4]) = make_uint2(0u, 0u);
    }

    for (int ci0 = 0; ci0 < Cn; ci0 += 32) {
        __syncthreads();
        // stage x[ci0..ci0+31][0..255] -> xT[t+2][ci-ci0] (bf16)
        // wave w handles ci rows w*8..w*8+7; lane l handles t = tt*64+l
        const float* xb = x + ((size_t)b * Cn + ci0 + w * 8) * Tn;
#pragma unroll
        for (int tt = 0; tt < 4; ++tt) {
            const int t = tt * 64 + l;
            float v[8];
#pragma unroll
            for (int rr = 0; rr < 8; ++rr) v[rr] = xb[rr * Tn + t];
            uint p0 = (uint)f2bf(v[0]) | ((uint)f2bf(v[1]) << 16);
            uint p1 = (uint)f2bf(v[2]) | ((uint)f2bf(v[3]) << 16);
            uint p2 = (uint)f2bf(v[4]) | ((uint)f2bf(v[5]) << 16);
            uint p3 = (uint)f2bf(v[6]) | ((uint)f2bf(v[7]) << 16);
            *reinterpret_cast<uint2*>(&xT[(t + 2) * 40 + w * 8])     = make_uint2(p0, p1);
            *reinterpret_cast<uint2*>(&xT[(t + 2) * 40 + w * 8 + 4]) = make_uint2(p2, p3);
        }
        __syncthreads();

#pragma unroll
        for (int k = 0; k < 5; ++k) {
            bf16x8 A[4];
#pragma unroll
            for (int m = 0; m < 4; ++m) {
                if (USE_WS) {
                    A[m] = *reinterpret_cast<const bf16x8*>(
                        Wws + (((size_t)((e * 5 + k) * 256 + cb + m * 16 + r)) << 8)
                            + ci0 + q * 8);
                } else {
                    bf16x8 a;
#pragma unroll
                    for (int j = 0; j < 8; ++j)
                        a[j] = (short)f2bf(
                            Wf[((size_t)((e * 256 + cb + m * 16 + r)) * 256
                                + ci0 + q * 8 + j) * 5 + k]);
                    A[m] = a;
                }
            }
#pragma unroll
            for (int n = 0; n < 4; ++n) {
                const bf16x8 Bf = *reinterpret_cast<const bf16x8*>(
                    &xT[(w * 64 + n * 16 + r + k) * 40 + q * 8]);
#pragma unroll
                for (int m = 0; m < 4; ++m)
                    acc[m][n] = __builtin_amdgcn_mfma_f32_16x16x32_bf16(
                        A[m], Bf, acc[m][n], 0, 0, 0);
            }
        }
    }

    // ---- bias + GroupNorm stats (group A: m 0,1 = co cb..cb+31; B: m 2,3) ----
    float s1a = 0.f, s2a = 0.f, s1b = 0.f, s2b = 0.f;
#pragma unroll
    for (int m = 0; m < 4; ++m) {
#pragma unroll
        for (int i = 0; i < 4; ++i) {
            const float bv = bias[e * 256 + cb + m * 16 + q * 4 + i];
#pragma unroll
            for (int n = 0; n < 4; ++n) {
                const float v = acc[m][n][i] + bv;
                acc[m][n][i] = v;
                if (m < 2) { s1a += v; s2a += v * v; }
                else       { s1b += v; s2b += v * v; }
            }
        }
    }
#pragma unroll
    for (int off = 32; off; off >>= 1) {
        s1a += __shfl_xor(s1a, off); s2a += __shfl_xor(s2a, off);
        s1b += __shfl_xor(s1b, off); s2b += __shfl_xor(s2b, off);
    }
    if (l == 0) { red[w][0] = s1a; red[w][1] = s2a; red[w][2] = s1b; red[w][3] = s2b; }
    __syncthreads();
    const float S1a = red[0][0] + red[1][0] + red[2][0] + red[3][0];
    const float S2a = red[0][1] + red[1][1] + red[2][1] + red[3][1];
    const float S1b = red[0][2] + red[1][2] + red[2][2] + red[3][2];
    const float S2b = red[0][3] + red[1][3] + red[2][3] + red[3][3];

    constexpr float invn = 1.0f / (32 * 256);
    const float mua = S1a * invn, mub = S1b * invn;
    const float rsa = rsqrtf(fmaf(-mua, mua, S2a * invn) + EPSf);
    const float rsb = rsqrtf(fmaf(-mub, mub, S2b * invn) + EPSf);

    // ---- normalize + Mish + store ----
#pragma unroll
    for (int m = 0; m < 4; ++m) {
        const float mu = (m < 2) ? mua : mub;
        const float rs = (m < 2) ? rsa : rsb;
#pragma unroll
        for (int i = 0; i < 4; ++i) {
            const int co = cb + m * 16 + q * 4 + i;
            const float sc = gamma[e * 256 + co] * rs;
            const float sh = beta[e * 256 + co] - mu * sc;
            float* orow = out + ((size_t)(b * 256 + co)) * 256 + w * 64 + r;
#pragma unroll
            for (int n = 0; n < 4; ++n) {
                const float y = fmaf(acc[m][n][i], sc, sh);
                // mish(y) = y*(u^2+2u)/(u^2+2u+2), u=e^y; y>20 -> y
                const float u  = __expf(y);
                const float t2 = u * (u + 2.f);
                const float ms = (y > 20.f) ? y : y * t2 / (t2 + 2.f);
                orow[n * 16] = ms;
            }
        }
    }
}

extern "C" void kernel_launch(void* const* d_in, const int* in_sizes, int n_in,
                              void* d_out, int out_size, void* d_ws, size_t ws_size,
                              hipStream_t stream) {
    const float* x      = (const float*)d_in[0];
    const int*   expert = (const int*)  d_in[1];
    const float* Wf     = (const float*)d_in[2];
    const float* bias   = (const float*)d_in[3];
    const float* gamma  = (const float*)d_in[4];
    const float* beta   = (const float*)d_in[5];
    float* out = (float*)d_out;

    const size_t W_BYTES = (size_t)En * 5 * 256 * 256 * 2;
    if (ws_size >= W_BYTES) {
        ushort* Wws = (ushort*)d_ws;
        hipLaunchKernelGGL(wconv_kernel, dim3(2048), dim3(256), 0, stream, Wf, Wws);
        hipLaunchKernelGGL((conv_mfma<true>), dim3(2048), dim3(256), 0, stream,
                           x, expert, Wf, Wws, bias, gamma, beta, out);
    } else {
        hipLaunchKernelGGL((conv_mfma<false>), dim3(2048), dim3(256), 0, stream,
                           x, expert, Wf, nullptr, bias, gamma, beta, out);
    }
}

// Round 3
// 225.197 us; speedup vs baseline: 5.3362x; 1.0139x over previous
//
#include <hip/hip_runtime.h>
#include <cmath>

constexpr int Bn = 512, Cn = 256, Tn = 256, En = 8;
constexpr float EPSf = 1e-5f;

using bf16x8 = __attribute__((ext_vector_type(8))) short;
using f32x4  = __attribute__((ext_vector_type(4))) float;

__device__ __forceinline__ ushort f2bf(float f) {
    uint u = __builtin_bit_cast(uint, f);
    uint r = u + 0x7FFFu + ((u >> 16) & 1u);   // RNE
    return (ushort)(r >> 16);
}

// Pre-kernel: W fp32 [E][co][ci][K] -> Wws bf16 [E][k][co][ci]
__global__ __launch_bounds__(256)
void wconv_kernel(const float* __restrict__ Wf, ushort* __restrict__ Wws) {
    int idx = blockIdx.x * 256 + threadIdx.x;   // e*65536 + co*256 + ci
    int ci = idx & 255, co = (idx >> 8) & 255, e = idx >> 16;
    const float* src = Wf + (size_t)idx * 5;
#pragma unroll
    for (int k = 0; k < 5; ++k)
        Wws[(((size_t)(e * 5 + k) * 256 + co) << 8) + ci] = f2bf(src[k]);
}

// Main: block = sample b. 512 threads = 8 waves (wm in 0..3 -> co 64-slice,
// wn in 0..1 -> t 128-slice). Per wave: 4 m x 8 n frags of 16x16 (128 acc VGPR).
// K = 8 tiles of 32 ci x 5 k. 2-phase pipeline: next tile's x loads issued
// to regs before current tile's MFMA; cvt+ds_write after the barrier.
// LDS: xT[t'][ci] bf16, t' = t+2 (halo rows 0,1,258,259 zero), row = 40 ushort.
template<bool USE_WS>
__global__ __launch_bounds__(512, 2)
void conv_mfma(const float* __restrict__ x, const int* __restrict__ expert,
               const float* __restrict__ Wf, const ushort* __restrict__ Wws,
               const float* __restrict__ bias, const float* __restrict__ gamma,
               const float* __restrict__ beta, float* __restrict__ out) {
    const int b = blockIdx.x;
    const int e = __builtin_amdgcn_readfirstlane(expert[b]);

    const int tid = threadIdx.x;
    const int w = tid >> 6, l = tid & 63, q = l >> 4, r = l & 15;
    const int wm = w >> 1, wn = w & 1;

    __shared__ ushort xT[260 * 40];
    __shared__ float red[8][4];

    f32x4 acc[4][8];
#pragma unroll
    for (int m = 0; m < 4; ++m)
#pragma unroll
        for (int n = 0; n < 8; ++n) acc[m][n] = f32x4{0.f, 0.f, 0.f, 0.f};

    // zero halo rows (t' = 0,1,258,259); never overwritten afterwards
    if (tid < 4) {
        int row = (tid < 2) ? tid : (256 + tid);
#pragma unroll
        for (int i = 0; i < 10; ++i)
            *reinterpret_cast<uint2*>(&xT[row * 40 + i * 4]) = make_uint2(0u, 0u);
    }

    float v[4][4];  // staging regs: [tt][rr] = x[ci0 + w*4 + rr][tt*64 + l]

#define STAGE_LOAD(CI0) {                                                   \
        const float* xb = x + ((size_t)b * Cn + (CI0) + w * 4) * Tn;        \
        _Pragma("unroll")                                                   \
        for (int tt = 0; tt < 4; ++tt) {                                    \
            const int t = tt * 64 + l;                                      \
            _Pragma("unroll")                                               \
            for (int rr = 0; rr < 4; ++rr) v[tt][rr] = xb[rr * Tn + t];     \
        }                                                                   \
    }
#define STAGE_WRITE() {                                                     \
        _Pragma("unroll")                                                   \
        for (int tt = 0; tt < 4; ++tt) {                                    \
            const int t = tt * 64 + l;                                      \
            uint p0 = (uint)f2bf(v[tt][0]) | ((uint)f2bf(v[tt][1]) << 16);  \
            uint p1 = (uint)f2bf(v[tt][2]) | ((uint)f2bf(v[tt][3]) << 16);  \
            *reinterpret_cast<uint2*>(&xT[(t + 2) * 40 + w * 4]) =          \
                make_uint2(p0, p1);                                         \
        }                                                                   \
    }

    STAGE_LOAD(0);
    __syncthreads();        // halo zeroing visible
    STAGE_WRITE();
    __syncthreads();

#pragma unroll 1
    for (int ct = 0; ct < 8; ++ct) {
        const int ci0 = ct * 32;
        if (ct < 7) STAGE_LOAD(ci0 + 32);   // in flight across the MFMA cluster

#pragma unroll
        for (int k = 0; k < 5; ++k) {
            bf16x8 A[4];
#pragma unroll
            for (int m = 0; m < 4; ++m) {
                if (USE_WS) {
                    A[m] = *reinterpret_cast<const bf16x8*>(
                        Wws + (((size_t)((e * 5 + k) * 256 + wm * 64 + m * 16 + r)) << 8)
                            + ci0 + q * 8);
                } else {
                    bf16x8 a;
#pragma unroll
                    for (int j = 0; j < 8; ++j)
                        a[j] = (short)f2bf(
                            Wf[((size_t)((e * 256 + wm * 64 + m * 16 + r)) * 256
                                + ci0 + q * 8 + j) * 5 + k]);
                    A[m] = a;
                }
            }
#pragma unroll
            for (int n = 0; n < 8; ++n) {
                const bf16x8 Bf = *reinterpret_cast<const bf16x8*>(
                    &xT[(wn * 128 + n * 16 + r + k) * 40 + q * 8]);
#pragma unroll
                for (int m = 0; m < 4; ++m)
                    acc[m][n] = __builtin_amdgcn_mfma_f32_16x16x32_bf16(
                        A[m], Bf, acc[m][n], 0, 0, 0);
            }
        }
        __syncthreads();                    // all waves done reading tile ct
        if (ct < 7) STAGE_WRITE();          // vmcnt drain lands here
        __syncthreads();
    }
#undef STAGE_LOAD
#undef STAGE_WRITE

    // ---- bias + GroupNorm stats ----
    // wave covers co [wm*64, wm*64+64) = groups 2wm (m 0,1) and 2wm+1 (m 2,3)
    float s1a = 0.f, s2a = 0.f, s1b = 0.f, s2b = 0.f;
#pragma unroll
    for (int m = 0; m < 4; ++m) {
#pragma unroll
        for (int i = 0; i < 4; ++i) {
            const float bv = bias[e * Cn + wm * 64 + m * 16 + q * 4 + i];
#pragma unroll
            for (int n = 0; n < 8; ++n) {
                const float vv = acc[m][n][i] + bv;
                acc[m][n][i] = vv;
                if (m < 2) { s1a += vv; s2a += vv * vv; }
                else       { s1b += vv; s2b += vv * vv; }
            }
        }
    }
#pragma unroll
    for (int off = 32; off; off >>= 1) {
        s1a += __shfl_xor(s1a, off); s2a += __shfl_xor(s2a, off);
        s1b += __shfl_xor(s1b, off); s2b += __shfl_xor(s2b, off);
    }
    if (l == 0) { red[w][0] = s1a; red[w][1] = s2a; red[w][2] = s1b; red[w][3] = s2b; }
    __syncthreads();
    // group 2wm: waves wm*2, wm*2+1 slots 0/1; group 2wm+1: slots 2/3
    const float S1a = red[wm * 2][0] + red[wm * 2 + 1][0];
    const float S2a = red[wm * 2][1] + red[wm * 2 + 1][1];
    const float S1b = red[wm * 2][2] + red[wm * 2 + 1][2];
    const float S2b = red[wm * 2][3] + red[wm * 2 + 1][3];

    constexpr float invn = 1.0f / (32 * 256);
    const float mua = S1a * invn, mub = S1b * invn;
    const float rsa = rsqrtf(fmaf(-mua, mua, S2a * invn) + EPSf);
    const float rsb = rsqrtf(fmaf(-mub, mub, S2b * invn) + EPSf);

    // ---- normalize + Mish + store ----
#pragma unroll
    for (int m = 0; m < 4; ++m) {
        const float mu = (m < 2) ? mua : mub;
        const float rs = (m < 2) ? rsa : rsb;
#pragma unroll
        for (int i = 0; i < 4; ++i) {
            const int co = wm * 64 + m * 16 + q * 4 + i;
            const float sc = gamma[e * Cn + co] * rs;
            const float sh = beta[e * Cn + co] - mu * sc;
            float* orow = out + ((size_t)(b * Cn + co)) * Tn + wn * 128 + r;
#pragma unroll
            for (int n = 0; n < 8; ++n) {
                const float y = fmaf(acc[m][n][i], sc, sh);
                const float u  = __expf(y);
                const float t2 = u * (u + 2.f);
                const float ms = (y > 20.f) ? y : y * t2 / (t2 + 2.f);
                orow[n * 16] = ms;
            }
        }
    }
}

extern "C" void kernel_launch(void* const* d_in, const int* in_sizes, int n_in,
                              void* d_out, int out_size, void* d_ws, size_t ws_size,
                              hipStream_t stream) {
    const float* x      = (const float*)d_in[0];
    const int*   expert = (const int*)  d_in[1];
    const float* Wf     = (const float*)d_in[2];
    const float* bias   = (const float*)d_in[3];
    const float* gamma  = (const float*)d_in[4];
    const float* beta   = (const float*)d_in[5];
    float* out = (float*)d_out;

    const size_t W_BYTES = (size_t)En * 5 * 256 * 256 * 2;
    if (ws_size >= W_BYTES) {
        ushort* Wws = (ushort*)d_ws;
        hipLaunchKernelGGL(wconv_kernel, dim3(2048), dim3(256), 0, stream, Wf, Wws);
        hipLaunchKernelGGL((conv_mfma<true>), dim3(Bn), dim3(512), 0, stream,
                           x, expert, Wf, Wws, bias, gamma, beta, out);
    } else {
        hipLaunchKernelGGL((conv_mfma<false>), dim3(Bn), dim3(512), 0, stream,
                           x, expert, Wf, nullptr, bias, gamma, beta, out);
    }
}